// Round 17
// baseline (510.164 us; speedup 1.0000x reference)
//
#include <hip/hip_runtime.h>
#include <hip/hip_bf16.h>

// Problem constants
#define Tt 4096   // B*L tokens
#define Dd 1024   // model dim
#define Ee 8      // experts
#define Kk 2      // top-k
#define Ff 4096   // DFF

using f32x4  = __attribute__((ext_vector_type(4))) float;
using bf16x8 = __attribute__((ext_vector_type(8))) short;

__device__ __forceinline__ unsigned short f2bf(float f) {
    union { float fp; unsigned int u; } v; v.fp = f;
    unsigned int u = v.u;
    return (unsigned short)((u + 0x7FFFu + ((u >> 16) & 1u)) >> 16);  // RNE
}

__device__ __forceinline__ float b2f(unsigned short u) {
    union { float f; unsigned int i; } v; v.i = (unsigned)u << 16; return v.f;
}

__device__ __forceinline__ void gl16(const void* g, void* l) {
    __builtin_amdgcn_global_load_lds(
        (const __attribute__((address_space(1))) void*)g,
        (__attribute__((address_space(3))) void*)l, 16, 0, 0);
}

// ---------------- Router (+ x->bf16): logits fp64, softmax, top-2, renorm ----------------
__global__ void router_kernel(const float* __restrict__ x, const float* __restrict__ Wr,
                              int* __restrict__ ids, float* __restrict__ wts,
                              int* __restrict__ counts, unsigned short* __restrict__ xb) {
    const int t = blockIdx.x;
    const int lane = threadIdx.x;  // 64
    const float* xr = x + (size_t)t * Dd + lane * 16;
    float xv[16];
#pragma unroll
    for (int i = 0; i < 4; ++i) *(float4*)(xv + 4 * i) = *(const float4*)(xr + 4 * i);
    uint4 o0, o1;
    o0.x = (unsigned)f2bf(xv[0])  | ((unsigned)f2bf(xv[1])  << 16);
    o0.y = (unsigned)f2bf(xv[2])  | ((unsigned)f2bf(xv[3])  << 16);
    o0.z = (unsigned)f2bf(xv[4])  | ((unsigned)f2bf(xv[5])  << 16);
    o0.w = (unsigned)f2bf(xv[6])  | ((unsigned)f2bf(xv[7])  << 16);
    o1.x = (unsigned)f2bf(xv[8])  | ((unsigned)f2bf(xv[9])  << 16);
    o1.y = (unsigned)f2bf(xv[10]) | ((unsigned)f2bf(xv[11]) << 16);
    o1.z = (unsigned)f2bf(xv[12]) | ((unsigned)f2bf(xv[13]) << 16);
    o1.w = (unsigned)f2bf(xv[14]) | ((unsigned)f2bf(xv[15]) << 16);
    unsigned short* xo = xb + (size_t)t * Dd + lane * 16;
    *(uint4*)(xo) = o0;
    *(uint4*)(xo + 8) = o1;

    double dot[Ee];
#pragma unroll
    for (int e = 0; e < Ee; ++e) {
        const float* wr = Wr + e * Dd + lane * 16;
        double s = 0.0;
#pragma unroll
        for (int i = 0; i < 16; ++i) s += (double)xv[i] * (double)wr[i];
        dot[e] = s;
    }
#pragma unroll
    for (int off = 32; off >= 1; off >>= 1) {
#pragma unroll
        for (int e = 0; e < Ee; ++e) dot[e] += __shfl_xor(dot[e], off, 64);
    }
    if (lane == 0) {
        float lg[Ee];
#pragma unroll
        for (int e = 0; e < Ee; ++e) lg[e] = (float)dot[e];
        float m = lg[0];
        for (int e = 1; e < Ee; ++e) m = fmaxf(m, lg[e]);
        float ex[Ee]; float sum = 0.f;
        for (int e = 0; e < Ee; ++e) { ex[e] = expf(lg[e] - m); sum += ex[e]; }
        float s0 = -1.f, s1 = -1.f; int i0 = 0, i1 = 0;
        for (int e = 0; e < Ee; ++e) {
            float s = ex[e];
            if (s > s0)      { s1 = s0; i1 = i0; s0 = s; i0 = e; }
            else if (s > s1) { s1 = s; i1 = e; }
        }
        float inv = 1.f / sum;
        float sc0 = s0 * inv, sc1 = s1 * inv;
        float den = sc0 + sc1 + 1.1920929e-7f;
        ids[2 * t] = i0; ids[2 * t + 1] = i1;
        wts[2 * t] = sc0 / den; wts[2 * t + 1] = sc1 / den;
        atomicAdd(&counts[i0], 1);
        atomicAdd(&counts[i1], 1);
    }
}

// ---------------- Wg/Wu -> interleaved bf16 Wgu ----------------
__global__ void cvt_wgu(const float* __restrict__ Wg, const float* __restrict__ Wu,
                        unsigned short* __restrict__ Wgu) {
    size_t tid = (size_t)blockIdx.x * blockDim.x + threadIdx.x;
    size_t row = tid >> 7;          // 128 threads per 1024-elem row
    int dc  = (int)(tid & 127);
    int e   = (int)(row >> 13);     // 8192 rows/expert
    int j   = (int)(row & 8191);
    int fg = j >> 5, s = (j >> 4) & 1, fi = j & 15;
    int f  = fg * 16 + fi;
    const float* src = (s ? Wu : Wg) + ((size_t)e * Ff + f) * Dd + dc * 8;
    float4 a = *(const float4*)(src);
    float4 b = *(const float4*)(src + 4);
    uint4 o;
    o.x = (unsigned)f2bf(a.x) | ((unsigned)f2bf(a.y) << 16);
    o.y = (unsigned)f2bf(a.z) | ((unsigned)f2bf(a.w) << 16);
    o.z = (unsigned)f2bf(b.x) | ((unsigned)f2bf(b.y) << 16);
    o.w = (unsigned)f2bf(b.z) | ((unsigned)f2bf(b.w) << 16);
    *(uint4*)(Wgu + row * Dd + dc * 8) = o;
}

// ---------------- merged scan + scatter (single block): rows[pos] = 2*t+k ----------------
__global__ void scan_scatter_kernel(const int* __restrict__ counts, const int* __restrict__ ids,
                                    int* __restrict__ cursor, int* __restrict__ eoff,
                                    int* __restrict__ rows) {
    if (threadIdx.x == 0) {
        int acc = 0;
        for (int e = 0; e < Ee; ++e) { eoff[e] = acc; cursor[e] = acc; acc += counts[e]; }
        eoff[Ee] = acc;
    }
    __syncthreads();
    for (int t = threadIdx.x; t < Tt; t += blockDim.x) {
#pragma unroll
        for (int k = 0; k < Kk; ++k) {
            int e = ids[2 * t + k];
            int pos = atomicAdd(&cursor[e], 1);
            rows[pos] = 2 * t + k;
        }
    }
}

// =================== 256x256 BK=64 8-wave 4-phase counted-vmcnt GEMM body ===================
// r6-verified schedule, NT=16 (r16 config, best measured 486 us). m0/sK passed in so the
// kernel wrappers run a persistent my-loop (covers arbitrary ne; zero extra iterations for
// balanced routing). Ledger (r6): stages in tile t = B(t+1) [P1,P2], A(t+2) [P3,P4];
// tile-end vmcnt(4) drains B(t+1), leaves A(t+2); tail vmcnt(0) once t+2>=NT;
// A-WAR protected by end-P2 lgkm drain + barrier.

#define MFMA_BF16(a, b, c) __builtin_amdgcn_mfma_f32_16x16x32_bf16(a, b, c, 0, 0, 0)

template<bool G2>
__device__ __forceinline__ void gemm_body(unsigned short* Ls,
                                          const unsigned short* __restrict__ Abase,
                                          const unsigned short* __restrict__ Bbase,
                                          const int* __restrict__ rows,
                                          unsigned short* __restrict__ H,
                                          unsigned short* __restrict__ partial,
                                          int e, int off, int ne, int m0, int sK) {
    constexpr int KLEN = G2 ? Ff : Dd;   // physical A/B row length
    constexpr int NT   = 16;             // 1024 K per block, BK=64
    const int koff = sK << 10;
    const int n0  = blockIdx.x * 256;

    const int tid  = threadIdx.x;
    const int lane = tid & 63;
    const int w    = tid >> 6;        // wave 0..7
    const int wr   = w >> 2;          // 0..1 (M half)
    const int wc   = w & 3;           // 0..3 (N quarter)
    const int lr   = lane & 15;
    const int lc   = lane >> 4;       // 0..3

    const int sr = lane >> 3;                 // 0..7
    const int cA = (lane & 7) ^ sr;           // pre-swizzled source chunk
    int asrc[4];
#pragma unroll
    for (int qq = 0; qq < 4; ++qq) {
        int rr = m0 + qq * 64 + w * 8 + sr;
        if (rr > ne - 1) rr = ne - 1;
        asrc[qq] = (G2 ? (off + rr) : (rows[off + rr] >> 1)) * KLEN + cA * 8;
    }
    const unsigned short* Bp = Bbase + (size_t)e * (G2 ? (size_t)Dd * Ff : (size_t)8192 * Dd);
    int bsrc[4];
#pragma unroll
    for (int qq = 0; qq < 4; ++qq) {
        int rN = n0 + qq * 64 + w * 8 + sr;
        bsrc[qq] = rN * KLEN + cA * 8;
    }

    auto STAGE_A = [&](int T, int Hh) {
        const int bo_ = (T & 1) * 32768; const int kt_ = koff + T * 64;
        gl16(Abase + asrc[2 * Hh]     + kt_, Ls + bo_ + (2 * Hh)     * 4096 + w * 512);
        gl16(Abase + asrc[2 * Hh + 1] + kt_, Ls + bo_ + (2 * Hh + 1) * 4096 + w * 512);
    };
    auto STAGE_B = [&](int T, int Hh) {
        const int bo_ = (T & 1) * 32768 + 16384; const int kt_ = koff + T * 64;
        gl16(Bp + bsrc[2 * Hh]     + kt_, Ls + bo_ + (2 * Hh)     * 4096 + w * 512);
        gl16(Bp + bsrc[2 * Hh + 1] + kt_, Ls + bo_ + (2 * Hh + 1) * 4096 + w * 512);
    };

    const int ccx0 = ((0 * 4 + lc) ^ (lr & 7)) * 8;
    const int ccx1 = ((1 * 4 + lc) ^ (lr & 7)) * 8;
    const int aB = wr * 8192 + lr * 64;
    const int bB = 16384 + wc * 4096 + lr * 64;

    f32x4 acc[8][4];
#pragma unroll
    for (int m = 0; m < 8; ++m)
#pragma unroll
        for (int n = 0; n < 4; ++n) acc[m][n] = (f32x4){0.f, 0.f, 0.f, 0.f};

    // --- prologue: tile0 fully + tile1 A; wait leaves A(1) (4 loads) in flight ---
    STAGE_A(0, 0); STAGE_A(0, 1); STAGE_B(0, 0); STAGE_B(0, 1);
    STAGE_A(1, 0); STAGE_A(1, 1);
    asm volatile("s_waitcnt vmcnt(4)" ::: "memory");
    __builtin_amdgcn_sched_barrier(0);
    __builtin_amdgcn_s_barrier();

    bf16x8 a0[8], a1[8], b0[4], b1[4];

    for (int t = 0; t < NT; ++t) {
        const int bo = (t & 1) * 32768;
        // ---- P1: read a_kk0 + b_kk0; stage (t+1).B0 ----
#pragma unroll
        for (int m = 0; m < 8; ++m) a0[m] = *(const bf16x8*)(Ls + bo + aB + m * 1024 + ccx0);
#pragma unroll
        for (int n = 0; n < 4; ++n) b0[n] = *(const bf16x8*)(Ls + bo + bB + n * 1024 + ccx0);
        if (t + 1 < NT) STAGE_B(t + 1, 0);
        __builtin_amdgcn_s_barrier();
        asm volatile("s_waitcnt lgkmcnt(0)" ::: "memory");
        __builtin_amdgcn_sched_barrier(0);
        __builtin_amdgcn_s_setprio(1);
#pragma unroll
        for (int m = 0; m < 8; ++m) {
            acc[m][0] = MFMA_BF16(a0[m], b0[0], acc[m][0]);
            acc[m][1] = MFMA_BF16(a0[m], b0[1], acc[m][1]);
        }
        __builtin_amdgcn_s_setprio(0);
        __builtin_amdgcn_s_barrier();
        // ---- P2: read a_kk1; stage (t+1).B1; MFMA kk0 nh1; REQUIRED lgkm-drain ----
#pragma unroll
        for (int m = 0; m < 8; ++m) a1[m] = *(const bf16x8*)(Ls + bo + aB + m * 1024 + ccx1);
        if (t + 1 < NT) STAGE_B(t + 1, 1);
        __builtin_amdgcn_s_barrier();
        __builtin_amdgcn_s_setprio(1);
#pragma unroll
        for (int m = 0; m < 8; ++m) {
            acc[m][2] = MFMA_BF16(a0[m], b0[2], acc[m][2]);
            acc[m][3] = MFMA_BF16(a0[m], b0[3], acc[m][3]);
        }
        __builtin_amdgcn_s_setprio(0);
        asm volatile("s_waitcnt lgkmcnt(0)" ::: "memory");
        __builtin_amdgcn_sched_barrier(0);
        __builtin_amdgcn_s_barrier();
        // ---- P3: read b_kk1; stage (t+2).A0; MFMA kk1 nh0 ----
#pragma unroll
        for (int n = 0; n < 4; ++n) b1[n] = *(const bf16x8*)(Ls + bo + bB + n * 1024 + ccx1);
        if (t + 2 < NT) STAGE_A(t + 2, 0);
        __builtin_amdgcn_s_barrier();
        asm volatile("s_waitcnt lgkmcnt(0)" ::: "memory");
        __builtin_amdgcn_sched_barrier(0);
        __builtin_amdgcn_s_setprio(1);
#pragma unroll
        for (int m = 0; m < 8; ++m) {
            acc[m][0] = MFMA_BF16(a1[m], b1[0], acc[m][0]);
            acc[m][1] = MFMA_BF16(a1[m], b1[1], acc[m][1]);
        }
        __builtin_amdgcn_s_setprio(0);
        __builtin_amdgcn_s_barrier();
        // ---- P4: stage (t+2).A1; MFMA kk1 nh1; counted vmcnt (tail-corrected) ----
        if (t + 2 < NT) STAGE_A(t + 2, 1);
        __builtin_amdgcn_s_setprio(1);
#pragma unroll
        for (int m = 0; m < 8; ++m) {
            acc[m][2] = MFMA_BF16(a1[m], b1[2], acc[m][2]);
            acc[m][3] = MFMA_BF16(a1[m], b1[3], acc[m][3]);
        }
        __builtin_amdgcn_s_setprio(0);
        if (t + 2 < NT) { asm volatile("s_waitcnt vmcnt(4)" ::: "memory"); }
        else            { asm volatile("s_waitcnt vmcnt(0)" ::: "memory"); }
        __builtin_amdgcn_sched_barrier(0);
        __builtin_amdgcn_s_barrier();
    }

    if constexpr (!G2) {
        // ---- epilogue gemm1: h = relu(g)*u in-register, write H ----
        const int fg16 = ((n0 + wc * 64) >> 5) * 16 + lr;
#pragma unroll
        for (int m = 0; m < 8; ++m) {
            const int itok = m0 + wr * 128 + m * 16 + lc * 4;
#pragma unroll
            for (int r = 0; r < 4; ++r) {
                const int i = itok + r;
                if (i < ne) {
                    unsigned short* hp = H + (size_t)(off + i) * Ff;
#pragma unroll
                    for (int np = 0; np < 2; ++np) {
                        const float g = acc[m][2 * np][r];
                        const float u = acc[m][2 * np + 1][r];
                        hp[fg16 + np * 16] = f2bf(fmaxf(g, 0.f) * u);
                    }
                }
            }
        }
    } else {
        // ---- epilogue gemm2: bf16 stores of raw acc to partial[sK][2t+k][d] ----
        const int dbase = n0 + wc * 64;
#pragma unroll
        for (int m = 0; m < 8; ++m) {
            const int ib = m0 + wr * 128 + m * 16 + lc * 4;
#pragma unroll
            for (int r = 0; r < 4; ++r) {
                const int i = ib + r;
                if (i < ne) {
                    const int tr = rows[off + i];  // 2t+k, token-determined target
                    unsigned short* op = partial + ((size_t)sK * 8192 + tr) * Dd + dbase + lr;
#pragma unroll
                    for (int n = 0; n < 4; ++n) op[n * 16] = f2bf(acc[m][n][r]);
                }
            }
        }
    }
    __builtin_amdgcn_s_barrier();  // separate persistent-my iterations (epi vs next prologue)
}

// g1: gemm1 (persistent my, step 8) + folded Wd fp32->bf16 conversion tail
__global__ __launch_bounds__(512, 1)
void g1_moe(const unsigned short* __restrict__ xb, const unsigned short* __restrict__ Wgu,
            const int* __restrict__ eoff, const int* __restrict__ rows,
            unsigned short* __restrict__ H,
            const float* __restrict__ Wd, unsigned short* __restrict__ Wdb) {
    __shared__ __align__(16) unsigned short Ls[65536];  // 128 KiB
    const int e   = blockIdx.z;
    const int off = eoff[e];
    const int ne  = eoff[e + 1] - off;
    for (int my = blockIdx.y; my * 256 < ne; my += 8)
        gemm_body<false>(Ls, xb, Wgu, rows, H, nullptr, e, off, ne, my * 256, 0);
    // Wd convert slice: 2048 blocks x 16384 elems = 33.55M
    const int fb = blockIdx.x + gridDim.x * (blockIdx.y + gridDim.y * blockIdx.z);
    const size_t base = (size_t)fb * 16384;
#pragma unroll
    for (int it = 0; it < 4; ++it) {
        const size_t i = base + (size_t)it * 4096 + threadIdx.x * 8;
        float4 a = *(const float4*)(Wd + i);
        float4 b = *(const float4*)(Wd + i + 4);
        uint4 o;
        o.x = (unsigned)f2bf(a.x) | ((unsigned)f2bf(a.y) << 16);
        o.y = (unsigned)f2bf(a.z) | ((unsigned)f2bf(a.w) << 16);
        o.z = (unsigned)f2bf(b.x) | ((unsigned)f2bf(b.y) << 16);
        o.w = (unsigned)f2bf(b.z) | ((unsigned)f2bf(b.w) << 16);
        *(uint4*)(Wdb + i) = o;
    }
}

// g2: gemm2 split-K=4 (persistent my, step 5)
__global__ __launch_bounds__(512, 1)
void g2_moe(const unsigned short* __restrict__ H, const unsigned short* __restrict__ Wdb,
            const int* __restrict__ eoff, const int* __restrict__ rows,
            unsigned short* __restrict__ partial) {
    __shared__ __align__(16) unsigned short Ls[65536];  // 128 KiB
    const int e   = blockIdx.z;
    const int off = eoff[e];
    const int ne  = eoff[e + 1] - off;
    const int sK  = blockIdx.y & 3;
    for (int my = blockIdx.y >> 2; my * 256 < ne; my += 5)
        gemm_body<true>(Ls, H, Wdb, rows, nullptr, partial, e, off, ne, my * 256, sK);
}

// ---------------- deterministic combine over 4 bf16 K-slices ----------------
__global__ void reduce_kernel(const unsigned short* __restrict__ P, const float* __restrict__ wts,
                              float* __restrict__ out) {
    const size_t idx = (size_t)blockIdx.x * blockDim.x + threadIdx.x;  // Tt*Dd/8 threads
    const size_t t  = idx >> 7;
    const int   dq  = (int)(idx & 127);
    const float w0 = wts[2 * t], w1 = wts[2 * t + 1];
    float sa[8] = {0.f}, sb[8] = {0.f};
#pragma unroll
    for (int s = 0; s < 4; ++s) {
        bf16x8 a = *(const bf16x8*)(P + ((size_t)s * 8192 + 2 * t)     * Dd + dq * 8);
        bf16x8 b = *(const bf16x8*)(P + ((size_t)s * 8192 + 2 * t + 1) * Dd + dq * 8);
#pragma unroll
        for (int j = 0; j < 8; ++j) {
            sa[j] += b2f((unsigned short)a[j]);
            sb[j] += b2f((unsigned short)b[j]);
        }
    }
    float o[8];
#pragma unroll
    for (int j = 0; j < 8; ++j) o[j] = w0 * sa[j] + w1 * sb[j];
    float* op = out + t * Dd + dq * 8;
    *(float4*)(op)     = (float4){o[0], o[1], o[2], o[3]};
    *(float4*)(op + 4) = (float4){o[4], o[5], o[6], o[7]};
}

extern "C" void kernel_launch(void* const* d_in, const int* in_sizes, int n_in,
                              void* d_out, int out_size, void* d_ws, size_t ws_size,
                              hipStream_t stream) {
    const float* x  = (const float*)d_in[0];
    const float* Wr = (const float*)d_in[1];
    const float* Wg = (const float*)d_in[2];
    const float* Wu = (const float*)d_in[3];
    const float* Wd = (const float*)d_in[4];
    float* out = (float*)d_out;
    char* ws = (char*)d_ws;

    const size_t WELEM    = (size_t)Ee * Ff * Dd;            // 33.55M
    const size_t OFF_IDS  = 256;
    const size_t OFF_WTS  = OFF_IDS  + (size_t)Tt * 2 * 4;
    const size_t OFF_ROWS = OFF_WTS  + (size_t)Tt * 2 * 4;
    const size_t OFF_ROWW = OFF_ROWS + (size_t)Tt * Kk * 4;
    const size_t OFF_XB   = OFF_ROWW + (size_t)Tt * Kk * 4;
    const size_t OFF_H    = OFF_XB   + (size_t)Tt * Dd * 2;
    const size_t OFF_WGU  = OFF_H    + (size_t)Tt * Kk * Ff * 2;
    const size_t OFF_WD   = OFF_WGU  + WELEM * 2 * 2;        // Wgu = 2*WELEM bf16 (134 MB)
    const size_t NEED     = OFF_WD   + WELEM * 2;            // ~264 MiB
    if (ws_size < NEED) return;

    int* counts = (int*)ws;
    int* cursor = (int*)(ws + 32);
    int* eoff   = (int*)(ws + 64);
    int* ids    = (int*)(ws + OFF_IDS);
    float* wts  = (float*)(ws + OFF_WTS);
    int* rows   = (int*)(ws + OFF_ROWS);
    unsigned short* xb  = (unsigned short*)(ws + OFF_XB);
    unsigned short* H   = (unsigned short*)(ws + OFF_H);
    unsigned short* Wgu = (unsigned short*)(ws + OFF_WGU);
    unsigned short* Wdb = (unsigned short*)(ws + OFF_WD);
    unsigned short* partial = (unsigned short*)(ws + OFF_WGU);  // 4 x 16 MB bf16, aliases Wgu

    hipMemsetAsync(ws, 0, 256, stream);

    router_kernel      <<<Tt, 64, 0, stream>>>(x, Wr, ids, wts, counts, xb);
    scan_scatter_kernel<<<1, 256, 0, stream>>>(counts, ids, cursor, eoff, rows);

    cvt_wgu            <<<32768, 256, 0, stream>>>(Wg, Wu, Wgu);

    g1_moe <<<dim3(2 * Ff / 256, 8, Ee), 512, 0, stream>>>(
        xb, Wgu, eoff, rows, H, Wd, Wdb);
    g2_moe <<<dim3(Dd / 256, 20, Ee), 512, 0, stream>>>(
        H, Wdb, eoff, rows, partial);

    reduce_kernel <<<(Tt * Dd / 8) / 256, 256, 0, stream>>>(partial, wts, out);
}

// Round 18
// 486.763 us; speedup vs baseline: 1.0481x; 1.0481x over previous
//
#include <hip/hip_runtime.h>
#include <hip/hip_bf16.h>

// Problem constants
#define Tt 4096   // B*L tokens
#define Dd 1024   // model dim
#define Ee 8      // experts
#define Kk 2      // top-k
#define Ff 4096   // DFF

using f32x4  = __attribute__((ext_vector_type(4))) float;
using bf16x8 = __attribute__((ext_vector_type(8))) short;

__device__ __forceinline__ unsigned short f2bf(float f) {
    union { float fp; unsigned int u; } v; v.fp = f;
    unsigned int u = v.u;
    return (unsigned short)((u + 0x7FFFu + ((u >> 16) & 1u)) >> 16);  // RNE
}

__device__ __forceinline__ float b2f(unsigned short u) {
    union { float f; unsigned int i; } v; v.i = (unsigned)u << 16; return v.f;
}

__device__ __forceinline__ void gl16(const void* g, void* l) {
    __builtin_amdgcn_global_load_lds(
        (const __attribute__((address_space(1))) void*)g,
        (__attribute__((address_space(3))) void*)l, 16, 0, 0);
}

// ---------------- Router (+ x->bf16): logits fp64, softmax, top-2, renorm ----------------
__global__ void router_kernel(const float* __restrict__ x, const float* __restrict__ Wr,
                              int* __restrict__ ids, float* __restrict__ wts,
                              int* __restrict__ counts, unsigned short* __restrict__ xb) {
    const int t = blockIdx.x;
    const int lane = threadIdx.x;  // 64
    const float* xr = x + (size_t)t * Dd + lane * 16;
    float xv[16];
#pragma unroll
    for (int i = 0; i < 4; ++i) *(float4*)(xv + 4 * i) = *(const float4*)(xr + 4 * i);
    uint4 o0, o1;
    o0.x = (unsigned)f2bf(xv[0])  | ((unsigned)f2bf(xv[1])  << 16);
    o0.y = (unsigned)f2bf(xv[2])  | ((unsigned)f2bf(xv[3])  << 16);
    o0.z = (unsigned)f2bf(xv[4])  | ((unsigned)f2bf(xv[5])  << 16);
    o0.w = (unsigned)f2bf(xv[6])  | ((unsigned)f2bf(xv[7])  << 16);
    o1.x = (unsigned)f2bf(xv[8])  | ((unsigned)f2bf(xv[9])  << 16);
    o1.y = (unsigned)f2bf(xv[10]) | ((unsigned)f2bf(xv[11]) << 16);
    o1.z = (unsigned)f2bf(xv[12]) | ((unsigned)f2bf(xv[13]) << 16);
    o1.w = (unsigned)f2bf(xv[14]) | ((unsigned)f2bf(xv[15]) << 16);
    unsigned short* xo = xb + (size_t)t * Dd + lane * 16;
    *(uint4*)(xo) = o0;
    *(uint4*)(xo + 8) = o1;

    double dot[Ee];
#pragma unroll
    for (int e = 0; e < Ee; ++e) {
        const float* wr = Wr + e * Dd + lane * 16;
        double s = 0.0;
#pragma unroll
        for (int i = 0; i < 16; ++i) s += (double)xv[i] * (double)wr[i];
        dot[e] = s;
    }
#pragma unroll
    for (int off = 32; off >= 1; off >>= 1) {
#pragma unroll
        for (int e = 0; e < Ee; ++e) dot[e] += __shfl_xor(dot[e], off, 64);
    }
    if (lane == 0) {
        float lg[Ee];
#pragma unroll
        for (int e = 0; e < Ee; ++e) lg[e] = (float)dot[e];
        float m = lg[0];
        for (int e = 1; e < Ee; ++e) m = fmaxf(m, lg[e]);
        float ex[Ee]; float sum = 0.f;
        for (int e = 0; e < Ee; ++e) { ex[e] = expf(lg[e] - m); sum += ex[e]; }
        float s0 = -1.f, s1 = -1.f; int i0 = 0, i1 = 0;
        for (int e = 0; e < Ee; ++e) {
            float s = ex[e];
            if (s > s0)      { s1 = s0; i1 = i0; s0 = s; i0 = e; }
            else if (s > s1) { s1 = s; i1 = e; }
        }
        float inv = 1.f / sum;
        float sc0 = s0 * inv, sc1 = s1 * inv;
        float den = sc0 + sc1 + 1.1920929e-7f;
        ids[2 * t] = i0; ids[2 * t + 1] = i1;
        wts[2 * t] = sc0 / den; wts[2 * t + 1] = sc1 / den;
        atomicAdd(&counts[i0], 1);
        atomicAdd(&counts[i1], 1);
    }
}

// ---------------- Wg/Wu -> interleaved bf16 Wgu ----------------
__global__ void cvt_wgu(const float* __restrict__ Wg, const float* __restrict__ Wu,
                        unsigned short* __restrict__ Wgu) {
    size_t tid = (size_t)blockIdx.x * blockDim.x + threadIdx.x;
    size_t row = tid >> 7;          // 128 threads per 1024-elem row
    int dc  = (int)(tid & 127);
    int e   = (int)(row >> 13);     // 8192 rows/expert
    int j   = (int)(row & 8191);
    int fg = j >> 5, s = (j >> 4) & 1, fi = j & 15;
    int f  = fg * 16 + fi;
    const float* src = (s ? Wu : Wg) + ((size_t)e * Ff + f) * Dd + dc * 8;
    float4 a = *(const float4*)(src);
    float4 b = *(const float4*)(src + 4);
    uint4 o;
    o.x = (unsigned)f2bf(a.x) | ((unsigned)f2bf(a.y) << 16);
    o.y = (unsigned)f2bf(a.z) | ((unsigned)f2bf(a.w) << 16);
    o.z = (unsigned)f2bf(b.x) | ((unsigned)f2bf(b.y) << 16);
    o.w = (unsigned)f2bf(b.z) | ((unsigned)f2bf(b.w) << 16);
    *(uint4*)(Wgu + row * Dd + dc * 8) = o;
}

// ---------------- counts -> offsets + cursors ----------------
__global__ void scan_kernel(const int* __restrict__ counts, int* __restrict__ cursor,
                            int* __restrict__ eoff) {
    if (threadIdx.x == 0) {
        int acc = 0;
        for (int e = 0; e < Ee; ++e) { eoff[e] = acc; cursor[e] = acc; acc += counts[e]; }
        eoff[Ee] = acc;
    }
}

// ---------------- scatter: rows[pos] = 2*t+k ----------------
__global__ void scatter_kernel(const int* __restrict__ ids,
                               int* __restrict__ cursor, int* __restrict__ rows) {
    int t = blockIdx.x * blockDim.x + threadIdx.x;
    if (t >= Tt) return;
#pragma unroll
    for (int k = 0; k < Kk; ++k) {
        int e = ids[2 * t + k];
        int pos = atomicAdd(&cursor[e], 1);
        rows[pos] = 2 * t + k;
    }
}

// =================== 256x256 BK=64 8-wave 4-phase counted-vmcnt GEMM body ===================
// r6-verified schedule, NT=16 for BOTH instantiations (uniform proven register/LDS shape).
// G1: A=xb via rows[]>>1 (KLEN=1024), B=Wgu (N=8192), koff=0, epi relu(g)*u -> H.
// G2: A=H direct (KLEN=4096), B=Wdb (N=1024), split-K=4: sK=by&3, koff=sK*1024,
//     epi bf16 stores of raw acc -> partial[sK][2t+k][d].
// Ledger (r6): stages in tile t = B(t+1) [P1,P2], A(t+2) [P3,P4]; tile-end vmcnt(4) drains
// B(t+1), leaves A(t+2); tail vmcnt(0) once t+2>=NT; A-WAR protected by end-P2 lgkm drain.

#define MFMA_BF16(a, b, c) __builtin_amdgcn_mfma_f32_16x16x32_bf16(a, b, c, 0, 0, 0)

template<bool G2>
__device__ __forceinline__ void gemm_body(unsigned short* Ls,
                                          const unsigned short* __restrict__ Abase,
                                          const unsigned short* __restrict__ Bbase,
                                          const int* __restrict__ eoff,
                                          const int* __restrict__ rows,
                                          unsigned short* __restrict__ H,
                                          unsigned short* __restrict__ partial) {
    constexpr int KLEN = G2 ? Ff : Dd;   // physical A/B row length
    constexpr int NT   = 16;             // 1024 K per block, BK=64
    const int e   = blockIdx.z;
    const int off = eoff[e];
    const int ne  = eoff[e + 1] - off;
    const int by  = blockIdx.y;
    const int my  = G2 ? (by >> 2) : by;
    const int sK  = G2 ? (by & 3) : 0;
    const int koff = sK * 1024;
    const int m0  = my * 256;
    if (m0 >= ne) return;
    const int n0  = blockIdx.x * 256;

    const int tid  = threadIdx.x;
    const int lane = tid & 63;
    const int w    = tid >> 6;        // wave 0..7
    const int wr   = w >> 2;          // 0..1 (M half)
    const int wc   = w & 3;           // 0..3 (N quarter)
    const int lr   = lane & 15;
    const int lc   = lane >> 4;       // 0..3

    const int sr = lane >> 3;                 // 0..7
    const int cA = (lane & 7) ^ sr;           // pre-swizzled source chunk
    int asrc[4];
#pragma unroll
    for (int qq = 0; qq < 4; ++qq) {
        int rr = m0 + qq * 64 + w * 8 + sr;
        if (rr > ne - 1) rr = ne - 1;
        asrc[qq] = (G2 ? (off + rr) : (rows[off + rr] >> 1)) * KLEN + cA * 8;
    }
    const unsigned short* Bp = Bbase + (size_t)e * (G2 ? (size_t)Dd * Ff : (size_t)8192 * Dd);
    int bsrc[4];
#pragma unroll
    for (int qq = 0; qq < 4; ++qq) {
        int rN = n0 + qq * 64 + w * 8 + sr;
        bsrc[qq] = rN * KLEN + cA * 8;
    }

    auto STAGE_A = [&](int T, int Hh) {
        const int bo_ = (T & 1) * 32768; const int kt_ = koff + T * 64;
        gl16(Abase + asrc[2 * Hh]     + kt_, Ls + bo_ + (2 * Hh)     * 4096 + w * 512);
        gl16(Abase + asrc[2 * Hh + 1] + kt_, Ls + bo_ + (2 * Hh + 1) * 4096 + w * 512);
    };
    auto STAGE_B = [&](int T, int Hh) {
        const int bo_ = (T & 1) * 32768 + 16384; const int kt_ = koff + T * 64;
        gl16(Bp + bsrc[2 * Hh]     + kt_, Ls + bo_ + (2 * Hh)     * 4096 + w * 512);
        gl16(Bp + bsrc[2 * Hh + 1] + kt_, Ls + bo_ + (2 * Hh + 1) * 4096 + w * 512);
    };

    const int ccx0 = ((0 * 4 + lc) ^ (lr & 7)) * 8;
    const int ccx1 = ((1 * 4 + lc) ^ (lr & 7)) * 8;
    const int aB = wr * 8192 + lr * 64;
    const int bB = 16384 + wc * 4096 + lr * 64;

    f32x4 acc[8][4];
#pragma unroll
    for (int m = 0; m < 8; ++m)
#pragma unroll
        for (int n = 0; n < 4; ++n) acc[m][n] = (f32x4){0.f, 0.f, 0.f, 0.f};

    // --- prologue: tile0 fully + tile1 A; wait leaves A(1) (4 loads) in flight ---
    STAGE_A(0, 0); STAGE_A(0, 1); STAGE_B(0, 0); STAGE_B(0, 1);
    STAGE_A(1, 0); STAGE_A(1, 1);
    asm volatile("s_waitcnt vmcnt(4)" ::: "memory");
    __builtin_amdgcn_sched_barrier(0);
    __builtin_amdgcn_s_barrier();

    bf16x8 a0[8], a1[8], b0[4], b1[4];

    for (int t = 0; t < NT; ++t) {
        const int bo = (t & 1) * 32768;
        // ---- P1: read a_kk0 + b_kk0; stage (t+1).B0 ----
#pragma unroll
        for (int m = 0; m < 8; ++m) a0[m] = *(const bf16x8*)(Ls + bo + aB + m * 1024 + ccx0);
#pragma unroll
        for (int n = 0; n < 4; ++n) b0[n] = *(const bf16x8*)(Ls + bo + bB + n * 1024 + ccx0);
        if (t + 1 < NT) STAGE_B(t + 1, 0);
        __builtin_amdgcn_s_barrier();
        asm volatile("s_waitcnt lgkmcnt(0)" ::: "memory");
        __builtin_amdgcn_sched_barrier(0);
        __builtin_amdgcn_s_setprio(1);
#pragma unroll
        for (int m = 0; m < 8; ++m) {
            acc[m][0] = MFMA_BF16(a0[m], b0[0], acc[m][0]);
            acc[m][1] = MFMA_BF16(a0[m], b0[1], acc[m][1]);
        }
        __builtin_amdgcn_s_setprio(0);
        __builtin_amdgcn_s_barrier();
        // ---- P2: read a_kk1; stage (t+1).B1; MFMA kk0 nh1; REQUIRED lgkm-drain ----
#pragma unroll
        for (int m = 0; m < 8; ++m) a1[m] = *(const bf16x8*)(Ls + bo + aB + m * 1024 + ccx1);
        if (t + 1 < NT) STAGE_B(t + 1, 1);
        __builtin_amdgcn_s_barrier();
        __builtin_amdgcn_s_setprio(1);
#pragma unroll
        for (int m = 0; m < 8; ++m) {
            acc[m][2] = MFMA_BF16(a0[m], b0[2], acc[m][2]);
            acc[m][3] = MFMA_BF16(a0[m], b0[3], acc[m][3]);
        }
        __builtin_amdgcn_s_setprio(0);
        asm volatile("s_waitcnt lgkmcnt(0)" ::: "memory");
        __builtin_amdgcn_sched_barrier(0);
        __builtin_amdgcn_s_barrier();
        // ---- P3: read b_kk1; stage (t+2).A0; MFMA kk1 nh0 ----
#pragma unroll
        for (int n = 0; n < 4; ++n) b1[n] = *(const bf16x8*)(Ls + bo + bB + n * 1024 + ccx1);
        if (t + 2 < NT) STAGE_A(t + 2, 0);
        __builtin_amdgcn_s_barrier();
        asm volatile("s_waitcnt lgkmcnt(0)" ::: "memory");
        __builtin_amdgcn_sched_barrier(0);
        __builtin_amdgcn_s_setprio(1);
#pragma unroll
        for (int m = 0; m < 8; ++m) {
            acc[m][0] = MFMA_BF16(a1[m], b1[0], acc[m][0]);
            acc[m][1] = MFMA_BF16(a1[m], b1[1], acc[m][1]);
        }
        __builtin_amdgcn_s_setprio(0);
        __builtin_amdgcn_s_barrier();
        // ---- P4: stage (t+2).A1; MFMA kk1 nh1; counted vmcnt (tail-corrected) ----
        if (t + 2 < NT) STAGE_A(t + 2, 1);
        __builtin_amdgcn_s_setprio(1);
#pragma unroll
        for (int m = 0; m < 8; ++m) {
            acc[m][2] = MFMA_BF16(a1[m], b1[2], acc[m][2]);
            acc[m][3] = MFMA_BF16(a1[m], b1[3], acc[m][3]);
        }
        __builtin_amdgcn_s_setprio(0);
        if (t + 2 < NT) { asm volatile("s_waitcnt vmcnt(4)" ::: "memory"); }
        else            { asm volatile("s_waitcnt vmcnt(0)" ::: "memory"); }
        __builtin_amdgcn_sched_barrier(0);
        __builtin_amdgcn_s_barrier();
    }

    if constexpr (!G2) {
        // ---- epilogue gemm1: h = relu(g)*u in-register, write H ----
        const int fg16 = ((n0 + wc * 64) >> 5) * 16 + lr;
#pragma unroll
        for (int m = 0; m < 8; ++m) {
            const int itok = m0 + wr * 128 + m * 16 + lc * 4;
#pragma unroll
            for (int r = 0; r < 4; ++r) {
                const int i = itok + r;
                if (i < ne) {
                    unsigned short* hp = H + (size_t)(off + i) * Ff;
#pragma unroll
                    for (int np = 0; np < 2; ++np) {
                        const float g = acc[m][2 * np][r];
                        const float u = acc[m][2 * np + 1][r];
                        hp[fg16 + np * 16] = f2bf(fmaxf(g, 0.f) * u);
                    }
                }
            }
        }
    } else {
        // ---- epilogue gemm2: bf16 stores of raw acc to partial[sK][2t+k][d] ----
        const int dbase = n0 + wc * 64;
#pragma unroll
        for (int m = 0; m < 8; ++m) {
            const int ib = m0 + wr * 128 + m * 16 + lc * 4;
#pragma unroll
            for (int r = 0; r < 4; ++r) {
                const int i = ib + r;
                if (i < ne) {
                    const int tr = rows[off + i];  // 2t+k, token-determined target
                    unsigned short* op = partial + ((size_t)sK * 8192 + tr) * Dd + dbase + lr;
#pragma unroll
                    for (int n = 0; n < 4; ++n) op[n * 16] = f2bf(acc[m][n][r]);
                }
            }
        }
    }
}

// g1: gemm1 + folded Wd fp32->bf16 conversion tail (every block, incl. early-exit ones)
__global__ __launch_bounds__(512, 1)
void g1_moe(const unsigned short* __restrict__ xb, const unsigned short* __restrict__ Wgu,
            const int* __restrict__ eoff, const int* __restrict__ rows,
            unsigned short* __restrict__ H,
            const float* __restrict__ Wd, unsigned short* __restrict__ Wdb) {
    __shared__ __align__(16) unsigned short Ls[65536];  // 128 KiB
    gemm_body<false>(Ls, xb, Wgu, eoff, rows, H, nullptr);
    // Wd convert slice: 4096 blocks x 8192 elems = 33.55M
    const int fb = blockIdx.x + gridDim.x * (blockIdx.y + gridDim.y * blockIdx.z);
    const size_t base = (size_t)fb * 8192;
#pragma unroll
    for (int it = 0; it < 2; ++it) {
        const size_t i = base + (size_t)it * 4096 + threadIdx.x * 8;
        float4 a = *(const float4*)(Wd + i);
        float4 b = *(const float4*)(Wd + i + 4);
        uint4 o;
        o.x = (unsigned)f2bf(a.x) | ((unsigned)f2bf(a.y) << 16);
        o.y = (unsigned)f2bf(a.z) | ((unsigned)f2bf(a.w) << 16);
        o.z = (unsigned)f2bf(b.x) | ((unsigned)f2bf(b.y) << 16);
        o.w = (unsigned)f2bf(b.z) | ((unsigned)f2bf(b.w) << 16);
        *(uint4*)(Wdb + i) = o;
    }
}

__global__ __launch_bounds__(512, 1)
void g2_moe(const unsigned short* __restrict__ H, const unsigned short* __restrict__ Wdb,
            const int* __restrict__ eoff, const int* __restrict__ rows,
            unsigned short* __restrict__ partial) {
    __shared__ __align__(16) unsigned short Ls[65536];  // 128 KiB
    gemm_body<true>(Ls, H, Wdb, eoff, rows, nullptr, partial);
}

// ---------------- deterministic combine over 4 bf16 K-slices ----------------
__global__ void reduce_kernel(const unsigned short* __restrict__ P, const float* __restrict__ wts,
                              float* __restrict__ out) {
    const size_t idx = (size_t)blockIdx.x * blockDim.x + threadIdx.x;  // Tt*Dd/8 threads
    const size_t t  = idx >> 7;
    const int   dq  = (int)(idx & 127);
    const float w0 = wts[2 * t], w1 = wts[2 * t + 1];
    float sa[8] = {0.f}, sb[8] = {0.f};
#pragma unroll
    for (int s = 0; s < 4; ++s) {
        bf16x8 a = *(const bf16x8*)(P + ((size_t)s * 8192 + 2 * t)     * Dd + dq * 8);
        bf16x8 b = *(const bf16x8*)(P + ((size_t)s * 8192 + 2 * t + 1) * Dd + dq * 8);
#pragma unroll
        for (int j = 0; j < 8; ++j) {
            sa[j] += b2f((unsigned short)a[j]);
            sb[j] += b2f((unsigned short)b[j]);
        }
    }
    float o[8];
#pragma unroll
    for (int j = 0; j < 8; ++j) o[j] = w0 * sa[j] + w1 * sb[j];
    float* op = out + t * Dd + dq * 8;
    *(float4*)(op)     = (float4){o[0], o[1], o[2], o[3]};
    *(float4*)(op + 4) = (float4){o[4], o[5], o[6], o[7]};
}

extern "C" void kernel_launch(void* const* d_in, const int* in_sizes, int n_in,
                              void* d_out, int out_size, void* d_ws, size_t ws_size,
                              hipStream_t stream) {
    const float* x  = (const float*)d_in[0];
    const float* Wr = (const float*)d_in[1];
    const float* Wg = (const float*)d_in[2];
    const float* Wu = (const float*)d_in[3];
    const float* Wd = (const float*)d_in[4];
    float* out = (float*)d_out;
    char* ws = (char*)d_ws;

    const size_t WELEM    = (size_t)Ee * Ff * Dd;            // 33.55M
    const size_t OFF_IDS  = 256;
    const size_t OFF_WTS  = OFF_IDS  + (size_t)Tt * 2 * 4;
    const size_t OFF_ROWS = OFF_WTS  + (size_t)Tt * 2 * 4;
    const size_t OFF_ROWW = OFF_ROWS + (size_t)Tt * Kk * 4;
    const size_t OFF_XB   = OFF_ROWW + (size_t)Tt * Kk * 4;
    const size_t OFF_H    = OFF_XB   + (size_t)Tt * Dd * 2;
    const size_t OFF_WGU  = OFF_H    + (size_t)Tt * Kk * Ff * 2;
    const size_t OFF_WD   = OFF_WGU  + WELEM * 2 * 2;        // Wgu = 2*WELEM bf16 (134 MB)
    const size_t NEED     = OFF_WD   + WELEM * 2;            // ~264 MiB
    if (ws_size < NEED) return;

    int* counts = (int*)ws;
    int* cursor = (int*)(ws + 32);
    int* eoff   = (int*)(ws + 64);
    int* ids    = (int*)(ws + OFF_IDS);
    float* wts  = (float*)(ws + OFF_WTS);
    int* rows   = (int*)(ws + OFF_ROWS);
    unsigned short* xb  = (unsigned short*)(ws + OFF_XB);
    unsigned short* H   = (unsigned short*)(ws + OFF_H);
    unsigned short* Wgu = (unsigned short*)(ws + OFF_WGU);
    unsigned short* Wdb = (unsigned short*)(ws + OFF_WD);
    unsigned short* partial = (unsigned short*)(ws + OFF_WGU);  // 4 x 16 MB bf16 = 64 MB, aliases Wgu

    hipMemsetAsync(ws, 0, 256, stream);

    router_kernel  <<<Tt, 64, 0, stream>>>(x, Wr, ids, wts, counts, xb);
    scan_kernel    <<<1, 64, 0, stream>>>(counts, cursor, eoff);
    scatter_kernel <<<Tt / 256, 256, 0, stream>>>(ids, cursor, rows);

    cvt_wgu        <<<32768, 256, 0, stream>>>(Wg, Wu, Wgu);

    g1_moe <<<dim3(2 * Ff / 256, Tt / 256, Ee), 512, 0, stream>>>(
        xb, Wgu, eoff, rows, H, Wd, Wdb);
    // g2: MT=256, split-K=4 -> y = 4sK * 5my (my 0..4 covers ne<=1280; early-exit beyond)
    g2_moe <<<dim3(Dd / 256, 20, Ee), 512, 0, stream>>>(
        H, Wdb, eoff, rows, partial);

    reduce_kernel  <<<(Tt * Dd / 8) / 256, 256, 0, stream>>>(partial, wts, out);
}

// Round 19
// 472.400 us; speedup vs baseline: 1.0799x; 1.0304x over previous
//
#include <hip/hip_runtime.h>
#include <hip/hip_bf16.h>

// Problem constants
#define Tt 4096   // B*L tokens
#define Dd 1024   // model dim
#define Ee 8      // experts
#define Kk 2      // top-k
#define Ff 4096   // DFF

using f32x4  = __attribute__((ext_vector_type(4))) float;
using bf16x8 = __attribute__((ext_vector_type(8))) short;

__device__ __forceinline__ unsigned short f2bf(float f) {
    union { float fp; unsigned int u; } v; v.fp = f;
    unsigned int u = v.u;
    return (unsigned short)((u + 0x7FFFu + ((u >> 16) & 1u)) >> 16);  // RNE
}

__device__ __forceinline__ float b2f(unsigned short u) {
    union { float f; unsigned int i; } v; v.i = (unsigned)u << 16; return v.f;
}

__device__ __forceinline__ void gl16(const void* g, void* l) {
    __builtin_amdgcn_global_load_lds(
        (const __attribute__((address_space(1))) void*)g,
        (__attribute__((address_space(3))) void*)l, 16, 0, 0);
}

// ---------------- Router (+ x->bf16 + folded Wgu conversion tail) ----------------
__global__ void router_kernel(const float* __restrict__ x, const float* __restrict__ Wr,
                              int* __restrict__ ids, float* __restrict__ wts,
                              int* __restrict__ counts, unsigned short* __restrict__ xb,
                              const float* __restrict__ Wg, const float* __restrict__ Wu,
                              unsigned short* __restrict__ Wgu) {
    const int t = blockIdx.x;
    const int lane = threadIdx.x;  // 64
    const float* xr = x + (size_t)t * Dd + lane * 16;
    float xv[16];
#pragma unroll
    for (int i = 0; i < 4; ++i) *(float4*)(xv + 4 * i) = *(const float4*)(xr + 4 * i);
    uint4 o0, o1;
    o0.x = (unsigned)f2bf(xv[0])  | ((unsigned)f2bf(xv[1])  << 16);
    o0.y = (unsigned)f2bf(xv[2])  | ((unsigned)f2bf(xv[3])  << 16);
    o0.z = (unsigned)f2bf(xv[4])  | ((unsigned)f2bf(xv[5])  << 16);
    o0.w = (unsigned)f2bf(xv[6])  | ((unsigned)f2bf(xv[7])  << 16);
    o1.x = (unsigned)f2bf(xv[8])  | ((unsigned)f2bf(xv[9])  << 16);
    o1.y = (unsigned)f2bf(xv[10]) | ((unsigned)f2bf(xv[11]) << 16);
    o1.z = (unsigned)f2bf(xv[12]) | ((unsigned)f2bf(xv[13]) << 16);
    o1.w = (unsigned)f2bf(xv[14]) | ((unsigned)f2bf(xv[15]) << 16);
    unsigned short* xo = xb + (size_t)t * Dd + lane * 16;
    *(uint4*)(xo) = o0;
    *(uint4*)(xo + 8) = o1;

    double dot[Ee];
#pragma unroll
    for (int e = 0; e < Ee; ++e) {
        const float* wr = Wr + e * Dd + lane * 16;
        double s = 0.0;
#pragma unroll
        for (int i = 0; i < 16; ++i) s += (double)xv[i] * (double)wr[i];
        dot[e] = s;
    }
#pragma unroll
    for (int off = 32; off >= 1; off >>= 1) {
#pragma unroll
        for (int e = 0; e < Ee; ++e) dot[e] += __shfl_xor(dot[e], off, 64);
    }
    if (lane == 0) {
        float lg[Ee];
#pragma unroll
        for (int e = 0; e < Ee; ++e) lg[e] = (float)dot[e];
        float m = lg[0];
        for (int e = 1; e < Ee; ++e) m = fmaxf(m, lg[e]);
        float ex[Ee]; float sum = 0.f;
        for (int e = 0; e < Ee; ++e) { ex[e] = expf(lg[e] - m); sum += ex[e]; }
        float s0 = -1.f, s1 = -1.f; int i0 = 0, i1 = 0;
        for (int e = 0; e < Ee; ++e) {
            float s = ex[e];
            if (s > s0)      { s1 = s0; i1 = i0; s0 = s; i0 = e; }
            else if (s > s1) { s1 = s; i1 = e; }
        }
        float inv = 1.f / sum;
        float sc0 = s0 * inv, sc1 = s1 * inv;
        float den = sc0 + sc1 + 1.1920929e-7f;
        ids[2 * t] = i0; ids[2 * t + 1] = i1;
        wts[2 * t] = sc0 / den; wts[2 * t + 1] = sc1 / den;
        atomicAdd(&counts[i0], 1);
        atomicAdd(&counts[i1], 1);
    }

    // ---- folded Wgu conversion (grid-stride; 32 iterations/thread, coalesced 16B/lane) ----
    const size_t NTOT = (size_t)Ee * 8192 * 128;   // 8.39M chunk-slots of 8 elems
    const size_t nthr = (size_t)gridDim.x * 64;    // 262144
    for (size_t tid = (size_t)blockIdx.x * 64 + lane; tid < NTOT; tid += nthr) {
        size_t row = tid >> 7;          // 128 threads per 1024-elem row
        int dc  = (int)(tid & 127);
        int e   = (int)(row >> 13);     // 8192 rows/expert
        int j   = (int)(row & 8191);
        int fg = j >> 5, s = (j >> 4) & 1, fi = j & 15;
        int f  = fg * 16 + fi;
        const float* src = (s ? Wu : Wg) + ((size_t)e * Ff + f) * Dd + dc * 8;
        float4 a = *(const float4*)(src);
        float4 b = *(const float4*)(src + 4);
        uint4 o;
        o.x = (unsigned)f2bf(a.x) | ((unsigned)f2bf(a.y) << 16);
        o.y = (unsigned)f2bf(a.z) | ((unsigned)f2bf(a.w) << 16);
        o.z = (unsigned)f2bf(b.x) | ((unsigned)f2bf(b.y) << 16);
        o.w = (unsigned)f2bf(b.z) | ((unsigned)f2bf(b.w) << 16);
        *(uint4*)(Wgu + row * Dd + dc * 8) = o;
    }
}

// ---------------- counts -> offsets + cursors ----------------
__global__ void scan_kernel(const int* __restrict__ counts, int* __restrict__ cursor,
                            int* __restrict__ eoff) {
    if (threadIdx.x == 0) {
        int acc = 0;
        for (int e = 0; e < Ee; ++e) { eoff[e] = acc; cursor[e] = acc; acc += counts[e]; }
        eoff[Ee] = acc;
    }
}

// ---------------- scatter: rows[pos] = 2*t+k ----------------
__global__ void scatter_kernel(const int* __restrict__ ids,
                               int* __restrict__ cursor, int* __restrict__ rows) {
    int t = blockIdx.x * blockDim.x + threadIdx.x;
    if (t >= Tt) return;
#pragma unroll
    for (int k = 0; k < Kk; ++k) {
        int e = ids[2 * t + k];
        int pos = atomicAdd(&cursor[e], 1);
        rows[pos] = 2 * t + k;
    }
}

// =================== 256x256 BK=64 8-wave 4-phase counted-vmcnt GEMM body ===================
// r6-verified schedule, NT=16 for BOTH instantiations (r16 config, best measured 486 us).
// G1: A=xb via rows[]>>1 (KLEN=1024), B=Wgu (N=8192), koff=0, epi relu(g)*u -> H.
// G2: A=H direct (KLEN=4096), B=Wdb (N=1024), split-K=4: sK=by&3, koff=sK*1024,
//     epi bf16 stores of raw acc -> partial[sK][2t+k][d].
// Ledger (r6): stages in tile t = B(t+1) [P1,P2], A(t+2) [P3,P4]; tile-end vmcnt(4) drains
// B(t+1), leaves A(t+2); tail vmcnt(0) once t+2>=NT; A-WAR protected by end-P2 lgkm drain.

#define MFMA_BF16(a, b, c) __builtin_amdgcn_mfma_f32_16x16x32_bf16(a, b, c, 0, 0, 0)

template<bool G2>
__device__ __forceinline__ void gemm_body(unsigned short* Ls,
                                          const unsigned short* __restrict__ Abase,
                                          const unsigned short* __restrict__ Bbase,
                                          const int* __restrict__ eoff,
                                          const int* __restrict__ rows,
                                          unsigned short* __restrict__ H,
                                          unsigned short* __restrict__ partial) {
    constexpr int KLEN = G2 ? Ff : Dd;   // physical A/B row length
    constexpr int NT   = 16;             // 1024 K per block, BK=64
    const int e   = blockIdx.z;
    const int off = eoff[e];
    const int ne  = eoff[e + 1] - off;
    const int by  = blockIdx.y;
    const int my  = G2 ? (by >> 2) : by;
    const int sK  = G2 ? (by & 3) : 0;
    const int koff = sK * 1024;
    const int m0  = my * 256;
    if (m0 >= ne) return;
    const int n0  = blockIdx.x * 256;

    const int tid  = threadIdx.x;
    const int lane = tid & 63;
    const int w    = tid >> 6;        // wave 0..7
    const int wr   = w >> 2;          // 0..1 (M half)
    const int wc   = w & 3;           // 0..3 (N quarter)
    const int lr   = lane & 15;
    const int lc   = lane >> 4;       // 0..3

    const int sr = lane >> 3;                 // 0..7
    const int cA = (lane & 7) ^ sr;           // pre-swizzled source chunk
    int asrc[4];
#pragma unroll
    for (int qq = 0; qq < 4; ++qq) {
        int rr = m0 + qq * 64 + w * 8 + sr;
        if (rr > ne - 1) rr = ne - 1;
        asrc[qq] = (G2 ? (off + rr) : (rows[off + rr] >> 1)) * KLEN + cA * 8;
    }
    const unsigned short* Bp = Bbase + (size_t)e * (G2 ? (size_t)Dd * Ff : (size_t)8192 * Dd);
    int bsrc[4];
#pragma unroll
    for (int qq = 0; qq < 4; ++qq) {
        int rN = n0 + qq * 64 + w * 8 + sr;
        bsrc[qq] = rN * KLEN + cA * 8;
    }

    auto STAGE_A = [&](int T, int Hh) {
        const int bo_ = (T & 1) * 32768; const int kt_ = koff + T * 64;
        gl16(Abase + asrc[2 * Hh]     + kt_, Ls + bo_ + (2 * Hh)     * 4096 + w * 512);
        gl16(Abase + asrc[2 * Hh + 1] + kt_, Ls + bo_ + (2 * Hh + 1) * 4096 + w * 512);
    };
    auto STAGE_B = [&](int T, int Hh) {
        const int bo_ = (T & 1) * 32768 + 16384; const int kt_ = koff + T * 64;
        gl16(Bp + bsrc[2 * Hh]     + kt_, Ls + bo_ + (2 * Hh)     * 4096 + w * 512);
        gl16(Bp + bsrc[2 * Hh + 1] + kt_, Ls + bo_ + (2 * Hh + 1) * 4096 + w * 512);
    };

    const int ccx0 = ((0 * 4 + lc) ^ (lr & 7)) * 8;
    const int ccx1 = ((1 * 4 + lc) ^ (lr & 7)) * 8;
    const int aB = wr * 8192 + lr * 64;
    const int bB = 16384 + wc * 4096 + lr * 64;

    f32x4 acc[8][4];
#pragma unroll
    for (int m = 0; m < 8; ++m)
#pragma unroll
        for (int n = 0; n < 4; ++n) acc[m][n] = (f32x4){0.f, 0.f, 0.f, 0.f};

    // --- prologue: tile0 fully + tile1 A; wait leaves A(1) (4 loads) in flight ---
    STAGE_A(0, 0); STAGE_A(0, 1); STAGE_B(0, 0); STAGE_B(0, 1);
    STAGE_A(1, 0); STAGE_A(1, 1);
    asm volatile("s_waitcnt vmcnt(4)" ::: "memory");
    __builtin_amdgcn_sched_barrier(0);
    __builtin_amdgcn_s_barrier();

    bf16x8 a0[8], a1[8], b0[4], b1[4];

    for (int t = 0; t < NT; ++t) {
        const int bo = (t & 1) * 32768;
        // ---- P1: read a_kk0 + b_kk0; stage (t+1).B0 ----
#pragma unroll
        for (int m = 0; m < 8; ++m) a0[m] = *(const bf16x8*)(Ls + bo + aB + m * 1024 + ccx0);
#pragma unroll
        for (int n = 0; n < 4; ++n) b0[n] = *(const bf16x8*)(Ls + bo + bB + n * 1024 + ccx0);
        if (t + 1 < NT) STAGE_B(t + 1, 0);
        __builtin_amdgcn_s_barrier();
        asm volatile("s_waitcnt lgkmcnt(0)" ::: "memory");
        __builtin_amdgcn_sched_barrier(0);
        __builtin_amdgcn_s_setprio(1);
#pragma unroll
        for (int m = 0; m < 8; ++m) {
            acc[m][0] = MFMA_BF16(a0[m], b0[0], acc[m][0]);
            acc[m][1] = MFMA_BF16(a0[m], b0[1], acc[m][1]);
        }
        __builtin_amdgcn_s_setprio(0);
        __builtin_amdgcn_s_barrier();
        // ---- P2: read a_kk1; stage (t+1).B1; MFMA kk0 nh1; REQUIRED lgkm-drain ----
#pragma unroll
        for (int m = 0; m < 8; ++m) a1[m] = *(const bf16x8*)(Ls + bo + aB + m * 1024 + ccx1);
        if (t + 1 < NT) STAGE_B(t + 1, 1);
        __builtin_amdgcn_s_barrier();
        __builtin_amdgcn_s_setprio(1);
#pragma unroll
        for (int m = 0; m < 8; ++m) {
            acc[m][2] = MFMA_BF16(a0[m], b0[2], acc[m][2]);
            acc[m][3] = MFMA_BF16(a0[m], b0[3], acc[m][3]);
        }
        __builtin_amdgcn_s_setprio(0);
        asm volatile("s_waitcnt lgkmcnt(0)" ::: "memory");
        __builtin_amdgcn_sched_barrier(0);
        __builtin_amdgcn_s_barrier();
        // ---- P3: read b_kk1; stage (t+2).A0; MFMA kk1 nh0 ----
#pragma unroll
        for (int n = 0; n < 4; ++n) b1[n] = *(const bf16x8*)(Ls + bo + bB + n * 1024 + ccx1);
        if (t + 2 < NT) STAGE_A(t + 2, 0);
        __builtin_amdgcn_s_barrier();
        asm volatile("s_waitcnt lgkmcnt(0)" ::: "memory");
        __builtin_amdgcn_sched_barrier(0);
        __builtin_amdgcn_s_setprio(1);
#pragma unroll
        for (int m = 0; m < 8; ++m) {
            acc[m][0] = MFMA_BF16(a1[m], b1[0], acc[m][0]);
            acc[m][1] = MFMA_BF16(a1[m], b1[1], acc[m][1]);
        }
        __builtin_amdgcn_s_setprio(0);
        __builtin_amdgcn_s_barrier();
        // ---- P4: stage (t+2).A1; MFMA kk1 nh1; counted vmcnt (tail-corrected) ----
        if (t + 2 < NT) STAGE_A(t + 2, 1);
        __builtin_amdgcn_s_setprio(1);
#pragma unroll
        for (int m = 0; m < 8; ++m) {
            acc[m][2] = MFMA_BF16(a1[m], b1[2], acc[m][2]);
            acc[m][3] = MFMA_BF16(a1[m], b1[3], acc[m][3]);
        }
        __builtin_amdgcn_s_setprio(0);
        if (t + 2 < NT) { asm volatile("s_waitcnt vmcnt(4)" ::: "memory"); }
        else            { asm volatile("s_waitcnt vmcnt(0)" ::: "memory"); }
        __builtin_amdgcn_sched_barrier(0);
        __builtin_amdgcn_s_barrier();
    }

    if constexpr (!G2) {
        // ---- epilogue gemm1: h = relu(g)*u in-register, write H ----
        const int fg16 = ((n0 + wc * 64) >> 5) * 16 + lr;
#pragma unroll
        for (int m = 0; m < 8; ++m) {
            const int itok = m0 + wr * 128 + m * 16 + lc * 4;
#pragma unroll
            for (int r = 0; r < 4; ++r) {
                const int i = itok + r;
                if (i < ne) {
                    unsigned short* hp = H + (size_t)(off + i) * Ff;
#pragma unroll
                    for (int np = 0; np < 2; ++np) {
                        const float g = acc[m][2 * np][r];
                        const float u = acc[m][2 * np + 1][r];
                        hp[fg16 + np * 16] = f2bf(fmaxf(g, 0.f) * u);
                    }
                }
            }
        }
    } else {
        // ---- epilogue gemm2: bf16 stores of raw acc to partial[sK][2t+k][d] ----
        const int dbase = n0 + wc * 64;
#pragma unroll
        for (int m = 0; m < 8; ++m) {
            const int ib = m0 + wr * 128 + m * 16 + lc * 4;
#pragma unroll
            for (int r = 0; r < 4; ++r) {
                const int i = ib + r;
                if (i < ne) {
                    const int tr = rows[off + i];  // 2t+k, token-determined target
                    unsigned short* op = partial + ((size_t)sK * 8192 + tr) * Dd + dbase + lr;
#pragma unroll
                    for (int n = 0; n < 4; ++n) op[n * 16] = f2bf(acc[m][n][r]);
                }
            }
        }
    }
}

// g1: gemm1 + folded Wd fp32->bf16 conversion tail (every block, incl. early-exit ones)
__global__ __launch_bounds__(512, 1)
void g1_moe(const unsigned short* __restrict__ xb, const unsigned short* __restrict__ Wgu,
            const int* __restrict__ eoff, const int* __restrict__ rows,
            unsigned short* __restrict__ H,
            const float* __restrict__ Wd, unsigned short* __restrict__ Wdb) {
    __shared__ __align__(16) unsigned short Ls[65536];  // 128 KiB
    gemm_body<false>(Ls, xb, Wgu, eoff, rows, H, nullptr);
    // Wd convert slice: 4096 blocks x 8192 elems = 33.55M
    const int fb = blockIdx.x + gridDim.x * (blockIdx.y + gridDim.y * blockIdx.z);
    const size_t base = (size_t)fb * 8192;
#pragma unroll
    for (int it = 0; it < 2; ++it) {
        const size_t i = base + (size_t)it * 4096 + threadIdx.x * 8;
        float4 a = *(const float4*)(Wd + i);
        float4 b = *(const float4*)(Wd + i + 4);
        uint4 o;
        o.x = (unsigned)f2bf(a.x) | ((unsigned)f2bf(a.y) << 16);
        o.y = (unsigned)f2bf(a.z) | ((unsigned)f2bf(a.w) << 16);
        o.z = (unsigned)f2bf(b.x) | ((unsigned)f2bf(b.y) << 16);
        o.w = (unsigned)f2bf(b.z) | ((unsigned)f2bf(b.w) << 16);
        *(uint4*)(Wdb + i) = o;
    }
}

__global__ __launch_bounds__(512, 1)
void g2_moe(const unsigned short* __restrict__ H, const unsigned short* __restrict__ Wdb,
            const int* __restrict__ eoff, const int* __restrict__ rows,
            unsigned short* __restrict__ partial) {
    __shared__ __align__(16) unsigned short Ls[65536];  // 128 KiB
    gemm_body<true>(Ls, H, Wdb, eoff, rows, nullptr, partial);
}

// ---------------- deterministic combine over 4 bf16 K-slices ----------------
__global__ void reduce_kernel(const unsigned short* __restrict__ P, const float* __restrict__ wts,
                              float* __restrict__ out) {
    const size_t idx = (size_t)blockIdx.x * blockDim.x + threadIdx.x;  // Tt*Dd/8 threads
    const size_t t  = idx >> 7;
    const int   dq  = (int)(idx & 127);
    const float w0 = wts[2 * t], w1 = wts[2 * t + 1];
    float sa[8] = {0.f}, sb[8] = {0.f};
#pragma unroll
    for (int s = 0; s < 4; ++s) {
        bf16x8 a = *(const bf16x8*)(P + ((size_t)s * 8192 + 2 * t)     * Dd + dq * 8);
        bf16x8 b = *(const bf16x8*)(P + ((size_t)s * 8192 + 2 * t + 1) * Dd + dq * 8);
#pragma unroll
        for (int j = 0; j < 8; ++j) {
            sa[j] += b2f((unsigned short)a[j]);
            sb[j] += b2f((unsigned short)b[j]);
        }
    }
    float o[8];
#pragma unroll
    for (int j = 0; j < 8; ++j) o[j] = w0 * sa[j] + w1 * sb[j];
    float* op = out + t * Dd + dq * 8;
    *(float4*)(op)     = (float4){o[0], o[1], o[2], o[3]};
    *(float4*)(op + 4) = (float4){o[4], o[5], o[6], o[7]};
}

extern "C" void kernel_launch(void* const* d_in, const int* in_sizes, int n_in,
                              void* d_out, int out_size, void* d_ws, size_t ws_size,
                              hipStream_t stream) {
    const float* x  = (const float*)d_in[0];
    const float* Wr = (const float*)d_in[1];
    const float* Wg = (const float*)d_in[2];
    const float* Wu = (const float*)d_in[3];
    const float* Wd = (const float*)d_in[4];
    float* out = (float*)d_out;
    char* ws = (char*)d_ws;

    const size_t WELEM    = (size_t)Ee * Ff * Dd;            // 33.55M
    const size_t OFF_IDS  = 256;
    const size_t OFF_WTS  = OFF_IDS  + (size_t)Tt * 2 * 4;
    const size_t OFF_ROWS = OFF_WTS  + (size_t)Tt * 2 * 4;
    const size_t OFF_ROWW = OFF_ROWS + (size_t)Tt * Kk * 4;
    const size_t OFF_XB   = OFF_ROWW + (size_t)Tt * Kk * 4;
    const size_t OFF_H    = OFF_XB   + (size_t)Tt * Dd * 2;
    const size_t OFF_WGU  = OFF_H    + (size_t)Tt * Kk * Ff * 2;
    const size_t OFF_WD   = OFF_WGU  + WELEM * 2 * 2;        // Wgu = 2*WELEM bf16 (134 MB)
    const size_t NEED     = OFF_WD   + WELEM * 2;            // ~264 MiB
    if (ws_size < NEED) return;

    int* counts = (int*)ws;
    int* cursor = (int*)(ws + 32);
    int* eoff   = (int*)(ws + 64);
    int* ids    = (int*)(ws + OFF_IDS);
    float* wts  = (float*)(ws + OFF_WTS);
    int* rows   = (int*)(ws + OFF_ROWS);
    unsigned short* xb  = (unsigned short*)(ws + OFF_XB);
    unsigned short* H   = (unsigned short*)(ws + OFF_H);
    unsigned short* Wgu = (unsigned short*)(ws + OFF_WGU);
    unsigned short* Wdb = (unsigned short*)(ws + OFF_WD);
    unsigned short* partial = (unsigned short*)(ws + OFF_WGU);  // 4 x 16 MB bf16, aliases Wgu

    hipMemsetAsync(ws, 0, 256, stream);

    router_kernel  <<<Tt, 64, 0, stream>>>(x, Wr, ids, wts, counts, xb, Wg, Wu, Wgu);
    scan_kernel    <<<1, 64, 0, stream>>>(counts, cursor, eoff);
    scatter_kernel <<<Tt / 256, 256, 0, stream>>>(ids, cursor, rows);

    g1_moe <<<dim3(2 * Ff / 256, Tt / 256, Ee), 512, 0, stream>>>(
        xb, Wgu, eoff, rows, H, Wd, Wdb);
    // g2: MT=256, split-K=4 -> y = 4sK * 5my (my 0..4 covers ne<=1280; early-exit beyond)
    g2_moe <<<dim3(Dd / 256, 20, Ee), 512, 0, stream>>>(
        H, Wdb, eoff, rows, partial);

    reduce_kernel  <<<(Tt * Dd / 8) / 256, 256, 0, stream>>>(partial, wts, out);
}